// Round 15
// baseline (474.736 us; speedup 1.0000x reference)
//
#include <hip/hip_runtime.h>

#define NB 100000
#define NG 20000
#define EL 1000000
#define EX 200000
#define NSEG (2 * NB + NG)   // concatenated CSR rows: [line->bus | g2b->bus | b2g->gen]
#define NE (EL + 2 * EX)
#define TILE 2048
#define NTILES ((NSEG + TILE - 1) / TILE)   // 108 (must be <= 256)
#define WROW 72              // Wt row stride (ushorts)
#define WMAT (64 * WROW)     // 4608 ushorts per 64x64 matrix
#define AST 200              // A-tile row stride (ushorts)
#define FPB 128              // fill blocks per partition
#define PSEG (NSEG / 8)      // 27500 segments per partition

typedef __attribute__((ext_vector_type(8))) short bf16x8;
typedef __attribute__((ext_vector_type(4))) float f32x4;

static __device__ __forceinline__ int uni(int x) { return __builtin_amdgcn_readfirstlane(x); }
static __device__ __forceinline__ int ntl(const int* p) { return __builtin_nontemporal_load(p); }

static __device__ __forceinline__ unsigned short f2bf(float x) {   // RNE f32->bf16
    unsigned u = __float_as_uint(x);
    u += 0x7FFF + ((u >> 16) & 1);
    return (unsigned short)(u >> 16);
}
static __device__ __forceinline__ float bf2f(unsigned short s) {
    return __uint_as_float(((unsigned)s) << 16);
}

// ---- fp32 -> bf16 array convert ----
__global__ void cvt_kernel(const float* __restrict__ src, unsigned short* __restrict__ dst, int n) {
    int i = (blockIdx.x * blockDim.x + threadIdx.x) * 4;
    if (i < n) {
        float4 f = *(const float4*)(src + i);
        ushort4 u = { f2bf(f.x), f2bf(f.y), f2bf(f.z), f2bf(f.w) };
        *(ushort4*)(dst + i) = u;
    }
}

// ---- fused degree count over all three edge lists (nt loads: don't pollute L2) ----
__global__ void count_all_kernel(const int* __restrict__ ld, const int* __restrict__ gd,
                                 const int* __restrict__ bd, int* __restrict__ deg) {
    int i = blockIdx.x * blockDim.x + threadIdx.x;
    if (i < EL)               atomicAdd(&deg[ntl(ld + i)], 1);
    else if (i < EL + EX)     atomicAdd(&deg[NB + ntl(gd + (i - EL))], 1);
    else if (i < NE)          atomicAdd(&deg[2 * NB + ntl(bd + (i - EL - EX))], 1);
}

// ---- hierarchical scan ----
__global__ __launch_bounds__(256) void scan_part_kernel(const int* __restrict__ deg,
                                                        int* __restrict__ partial, int n) {
    __shared__ int ls[256];
    const int t = threadIdx.x;
    const int base = blockIdx.x * TILE;
    int s = 0;
    for (int i = t; i < TILE; i += 256) {
        int idx = base + i;
        s += (idx < n) ? deg[idx] : 0;
    }
    ls[t] = s;
    __syncthreads();
    for (int d = 128; d > 0; d >>= 1) {
        if (t < d) ls[t] += ls[t + d];
        __syncthreads();
    }
    if (t == 0) partial[blockIdx.x] = ls[0];
}

__global__ __launch_bounds__(256) void scan_top_kernel(int* __restrict__ partial,
                                                       int* __restrict__ off, int nparts, int n) {
    __shared__ int ls[256];
    const int t = threadIdx.x;
    ls[t] = (t < nparts) ? partial[t] : 0;
    __syncthreads();
    for (int d = 1; d < 256; d <<= 1) {
        int x = (t >= d) ? ls[t - d] : 0;
        __syncthreads();
        ls[t] += x;
        __syncthreads();
    }
    if (t < nparts) partial[t] = (t == 0) ? 0 : ls[t - 1];
    if (t == 255) off[n] = ls[255];
}

__global__ __launch_bounds__(256) void scan_write_kernel(const int* __restrict__ deg,
                                                         const int* __restrict__ partial,
                                                         int* __restrict__ off,
                                                         int* __restrict__ cur, int n) {
    __shared__ int ls[256];
    const int t = threadIdx.x;
    const int b0 = blockIdx.x * TILE + t * 8;
    int local[8];
    int s = 0;
#pragma unroll
    for (int j = 0; j < 8; ++j) {
        int idx = b0 + j;
        local[j] = (idx < n) ? deg[idx] : 0;
        s += local[j];
    }
    ls[t] = s;
    __syncthreads();
    for (int d = 1; d < 256; d <<= 1) {
        int x = (t >= d) ? ls[t - d] : 0;
        __syncthreads();
        ls[t] += x;
        __syncthreads();
    }
    int run = partial[blockIdx.x] + ((t == 0) ? 0 : ls[t - 1]);
#pragma unroll
    for (int j = 0; j < 8; ++j) {
        int idx = b0 + j;
        if (idx < n) { off[idx] = run; cur[idx] = run; run += local[j]; }
    }
}

// ---- partitioned CSR fill (R12 structure, 67 µs) + nt edge reads.
//      R14 WRITE=63.8 MB for 5.6 MB payload: per-partition elist regions (0.7 MB)
//      fit L2, so partial write lines are evicted by the 90 MB STREAMING READ of
//      edge arrays — nt loads keep those reads out of L2 so write lines fill. ----
__global__ __launch_bounds__(256) void fill_part_kernel(
    const int* __restrict__ ls, const int* __restrict__ ld,
    const int* __restrict__ gs, const int* __restrict__ gd,
    const int* __restrict__ bs, const int* __restrict__ bd,
    int* __restrict__ cursor, int* __restrict__ elist)
{
    const int p = blockIdx.x & 7;
    const int q = blockIdx.x >> 3;
    const int lo = p * PSEG;
    const int hi = lo + PSEG;
    for (int i = q * 256 + threadIdx.x; i < NE; i += FPB * 256) {
        int src, seg;
        if (i < EL)           { src = ntl(ls + i);            seg = ntl(ld + i); }
        else if (i < EL + EX) { src = ntl(gs + (i - EL));     seg = NB + ntl(gd + (i - EL)); }
        else                  { src = ntl(bs + (i - EL - EX)); seg = 2 * NB + ntl(bd + (i - EL - EX)); }
        if (seg >= lo && seg < hi) {
            int pos = atomicAdd(&cursor[seg], 1);
            elist[pos] = src;
        }
    }
}

// ---- weight prep: Wt[n*72+k] = bf16(W[k*64+n]) for 10 matrices (one block each) ----
struct WPrep { const float* src[10]; unsigned short* dst[10]; };
__global__ __launch_bounds__(256) void wprep_kernel(WPrep p) {
    const float* __restrict__ s = p.src[blockIdx.x];
    unsigned short* __restrict__ d = p.dst[blockIdx.x];
    for (int idx = threadIdx.x; idx < 4096; idx += 256) {
        int k = idx >> 6, nn = idx & 63;
        d[nn * WROW + k] = f2bf(s[idx]);
    }
}

// ---- mean over bf16 CSR segment, 8 gathers in flight ----
static __device__ __forceinline__ float seg_mean16(const unsigned short* __restrict__ h,
                                                   const int* __restrict__ elist,
                                                   int s0, int e0, int lane) {
    float s = 0.f;
    int e = s0;
    for (; e + 8 <= e0; e += 8) {
        int i0 = elist[e],     i1 = elist[e + 1], i2 = elist[e + 2], i3 = elist[e + 3];
        int i4 = elist[e + 4], i5 = elist[e + 5], i6 = elist[e + 6], i7 = elist[e + 7];
        float v0 = bf2f(h[(size_t)i0 * 64 + lane]), v1 = bf2f(h[(size_t)i1 * 64 + lane]);
        float v2 = bf2f(h[(size_t)i2 * 64 + lane]), v3 = bf2f(h[(size_t)i3 * 64 + lane]);
        float v4 = bf2f(h[(size_t)i4 * 64 + lane]), v5 = bf2f(h[(size_t)i5 * 64 + lane]);
        float v6 = bf2f(h[(size_t)i6 * 64 + lane]), v7 = bf2f(h[(size_t)i7 * 64 + lane]);
        s += ((v0 + v1) + (v2 + v3)) + ((v4 + v5) + (v6 + v7));
    }
    for (; e + 2 <= e0; e += 2) {
        int i0 = elist[e], i1 = elist[e + 1];
        s += bf2f(h[(size_t)i0 * 64 + lane]) + bf2f(h[(size_t)i1 * 64 + lane]);
    }
    if (e < e0) s += bf2f(h[(size_t)elist[e] * 64 + lane]);
    return s / fmaxf((float)(e0 - s0), 1.f);
}

// ---- merged aggregation (R10 form; bf16 in/out) ----
__global__ __launch_bounds__(256) void aggr_all_kernel(
    const unsigned short* __restrict__ hb, const unsigned short* __restrict__ hg,
    const int* __restrict__ off, const int* __restrict__ elist,
    unsigned short* __restrict__ Aline, unsigned short* __restrict__ Ag2b,
    unsigned short* __restrict__ Ab2g)
{
    const int lane = threadIdx.x & 63;
    int w = uni(blockIdx.x * 4 + (threadIdx.x >> 6));
    if (w < NB) {
        Aline[(size_t)w * 64 + lane] = f2bf(seg_mean16(hb, elist, off[w], off[w + 1], lane));
        Ag2b[(size_t)w * 64 + lane]  = f2bf(seg_mean16(hg, elist, off[NB + w], off[NB + w + 1], lane));
    } else if (w < NB + NG) {
        int g = w - NB;
        Ab2g[(size_t)g * 64 + lane] = f2bf(seg_mean16(hb, elist, off[2 * NB + g], off[2 * NB + g + 1], lane));
    }
}

// ---- MFMA combine (R10-validated structure): out16 = bf16(relu([h|A1|A2] @ Wt^T + b)) ----
__global__ __launch_bounds__(256) void combine_mfma_kernel(
    const unsigned short* __restrict__ h, const unsigned short* __restrict__ A1,
    const unsigned short* __restrict__ A2,
    const unsigned short* __restrict__ Wt, const float* __restrict__ bias,
    unsigned short* __restrict__ out, float* __restrict__ pool, int n, int nmat)
{
    __shared__ __attribute__((aligned(16))) unsigned short Atile[64 * AST]; // 25.6 KB
    __shared__ __attribute__((aligned(16))) unsigned short Wtile[3 * WMAT]; // 27.6 KB
    __shared__ float pred[64];
    const int t = threadIdx.x;
    const int base = blockIdx.x * 64;

    if (t < 64) pred[t] = 0.f;

#pragma unroll
    for (int i = 0; i < 4; ++i) {
        int flat = i * 1024 + t * 4;
        int r = flat >> 6, c = flat & 63;
        bool ok = (base + r) < n;
        ushort4 z = {0, 0, 0, 0};
        size_t g = (size_t)(base + r) * 64 + c;
        *(ushort4*)&Atile[r * AST + c]      = ok ? *(const ushort4*)(h + g)  : z;
        *(ushort4*)&Atile[r * AST + 64 + c] = ok ? *(const ushort4*)(A1 + g) : z;
        if (nmat == 3)
            *(ushort4*)&Atile[r * AST + 128 + c] = ok ? *(const ushort4*)(A2 + g) : z;
    }
    {
        const int nv = nmat * (WMAT / 4);
        const ushort4* __restrict__ src = (const ushort4*)Wt;
        ushort4* dst = (ushort4*)Wtile;
        for (int idx = t; idx < nv; idx += 256) dst[idx] = src[idx];
    }
    __syncthreads();

    const int lane = t & 63;
    const int w = t >> 6;
    const int l15 = lane & 15;
    const int q = lane >> 4;
    f32x4 acc[4];
#pragma unroll
    for (int c = 0; c < 4; ++c) acc[c] = (f32x4){0.f, 0.f, 0.f, 0.f};

    const int ksteps = nmat * 2;
    for (int ks = 0; ks < ksteps; ++ks) {
        bf16x8 av = *(const bf16x8*)&Atile[(w * 16 + l15) * AST + ks * 32 + q * 8];
#pragma unroll
        for (int c = 0; c < 4; ++c) {
            bf16x8 bv = *(const bf16x8*)&Wtile[(ks >> 1) * WMAT + (c * 16 + l15) * WROW + (ks & 1) * 32 + q * 8];
            acc[c] = __builtin_amdgcn_mfma_f32_16x16x32_bf16(av, bv, acc[c], 0, 0, 0);
        }
    }

    if (pool == nullptr) {
#pragma unroll
        for (int c = 0; c < 4; ++c) {
            const int col = c * 16 + l15;
            const float bv = bias[col];
#pragma unroll
            for (int reg = 0; reg < 4; ++reg) {
                int row = base + w * 16 + q * 4 + reg;
                if (row < n) out[(size_t)row * 64 + col] = f2bf(fmaxf(acc[c][reg] + bv, 0.f));
            }
        }
    } else {
#pragma unroll
        for (int c = 0; c < 4; ++c) {
            const int col = c * 16 + l15;
            const float bv = bias[col];
            float s = 0.f;
#pragma unroll
            for (int reg = 0; reg < 4; ++reg) {
                int row = base + w * 16 + q * 4 + reg;
                if (row < n) s += fmaxf(acc[c][reg] + bv, 0.f);
            }
            atomicAdd(&pred[col], s);
        }
        __syncthreads();
        if (t < 64) atomicAdd(&pool[t], pred[t]);
    }
}

// ---- head: out = relu(g @ Wh + bh) @ Wo + bo ----
__global__ void head_kernel(const float* __restrict__ pool,
                            const float* __restrict__ Wh, const float* __restrict__ bh,
                            const float* __restrict__ Wo, const float* __restrict__ bo,
                            float* __restrict__ out)
{
    __shared__ float g[128];
    __shared__ float hid[64];
    int t = threadIdx.x;  // 128 threads
    g[t] = pool[t];
    __syncthreads();
    if (t < 64) {
        float a = bh[t];
        for (int i = 0; i < 128; ++i) a += g[i] * Wh[i * 64 + t];
        hid[t] = fmaxf(a, 0.f);
    }
    __syncthreads();
    if (t < 16) {
        float a = bo[t];
        for (int j = 0; j < 64; ++j) a += hid[j] * Wo[j * 16 + t];
        out[t] = a;
    }
}

extern "C" void kernel_launch(void* const* d_in, const int* in_sizes, int n_in,
                              void* d_out, int out_size, void* d_ws, size_t ws_size,
                              hipStream_t stream)
{
    const float* x_bus   = (const float*)d_in[0];
    const float* x_gen   = (const float*)d_in[1];
    const int* line_src  = (const int*)d_in[2];
    const int* line_dst  = (const int*)d_in[3];
    const int* g2b_src   = (const int*)d_in[4];
    const int* g2b_dst   = (const int*)d_in[5];
    const int* b2g_src   = (const int*)d_in[6];
    const int* b2g_dst   = (const int*)d_in[7];
    const float* Wsb[2]  = {(const float*)d_in[8],  (const float*)d_in[15]};
    const float* Wsg[2]  = {(const float*)d_in[9],  (const float*)d_in[16]};
    const float* Wl[2]   = {(const float*)d_in[10], (const float*)d_in[17]};
    const float* Wg2b[2] = {(const float*)d_in[11], (const float*)d_in[18]};
    const float* Wb2g[2] = {(const float*)d_in[12], (const float*)d_in[19]};
    const float* bsb[2]  = {(const float*)d_in[13], (const float*)d_in[20]};
    const float* bsg[2]  = {(const float*)d_in[14], (const float*)d_in[21]};
    const float* Wh = (const float*)d_in[22];
    const float* bh = (const float*)d_in[23];
    const float* Wo = (const float*)d_in[24];
    const float* bo = (const float*)d_in[25];
    (void)in_sizes; (void)n_in; (void)out_size; (void)ws_size;

    char* wsB = (char*)d_ws;
    size_t o = 0;
    auto alloc_f = [&](size_t nelem) { o = (o + 15) & ~(size_t)15; float* p = (float*)(wsB + o); o += nelem * sizeof(float); return p; };
    auto alloc_i = [&](size_t nelem) { o = (o + 15) & ~(size_t)15; int* p = (int*)(wsB + o); o += nelem * sizeof(int); return p; };
    auto alloc_u = [&](size_t nelem) { o = (o + 15) & ~(size_t)15; unsigned short* p = (unsigned short*)(wsB + o); o += nelem * sizeof(unsigned short); return p; };

    unsigned short* xb16  = alloc_u((size_t)NB * 64);
    unsigned short* xg16  = alloc_u((size_t)NG * 64);
    unsigned short* H1b   = alloc_u((size_t)NB * 64);
    unsigned short* H1g   = alloc_u((size_t)NG * 64);
    unsigned short* Aline = alloc_u((size_t)NB * 64);
    unsigned short* Ag2b  = alloc_u((size_t)NB * 64);
    unsigned short* Ab2g  = alloc_u((size_t)NG * 64);
    int*   elist = alloc_i(NE);
    int*   deg   = alloc_i(NSEG);
    int*   off   = alloc_i(NSEG + 1);
    int*   cur   = alloc_i(NSEG);
    int*   part  = alloc_i(256);
    float* pool  = alloc_f(128);
    unsigned short* WtBus[2] = { alloc_u(3 * WMAT), alloc_u(3 * WMAT) };
    unsigned short* WtGen[2] = { alloc_u(2 * WMAT), alloc_u(2 * WMAT) };

    // ---- weight prep + input convert (independent of CSR) ----
    WPrep wp;
    for (int l = 0; l < 2; ++l) {
        wp.src[l * 5 + 0] = Wsb[l];  wp.dst[l * 5 + 0] = WtBus[l] + 0 * WMAT;
        wp.src[l * 5 + 1] = Wl[l];   wp.dst[l * 5 + 1] = WtBus[l] + 1 * WMAT;
        wp.src[l * 5 + 2] = Wg2b[l]; wp.dst[l * 5 + 2] = WtBus[l] + 2 * WMAT;
        wp.src[l * 5 + 3] = Wsg[l];  wp.dst[l * 5 + 3] = WtGen[l] + 0 * WMAT;
        wp.src[l * 5 + 4] = Wb2g[l]; wp.dst[l * 5 + 4] = WtGen[l] + 1 * WMAT;
    }
    wprep_kernel<<<10, 256, 0, stream>>>(wp);
    cvt_kernel<<<(NB * 64 / 4 + 255) / 256, 256, 0, stream>>>(x_bus, xb16, NB * 64);
    cvt_kernel<<<(NG * 64 / 4 + 255) / 256, 256, 0, stream>>>(x_gen, xg16, NG * 64);

    // ---- CSR build ----
    hipMemsetAsync(deg, 0, NSEG * sizeof(int), stream);
    hipMemsetAsync(pool, 0, 128 * sizeof(float), stream);
    count_all_kernel<<<(NE + 255) / 256, 256, 0, stream>>>(line_dst, g2b_dst, b2g_dst, deg);
    scan_part_kernel<<<NTILES, 256, 0, stream>>>(deg, part, NSEG);
    scan_top_kernel<<<1, 256, 0, stream>>>(part, off, NTILES, NSEG);
    scan_write_kernel<<<NTILES, 256, 0, stream>>>(deg, part, off, cur, NSEG);
    fill_part_kernel<<<8 * FPB, 256, 0, stream>>>(line_src, line_dst, g2b_src, g2b_dst,
                                                  b2g_src, b2g_dst, cur, elist);

    const int gaA = (NB + NG + 3) / 4;
    const int tbB = (NB + 63) / 64, tbG = (NG + 63) / 64;

    // ---- layer 0 ----
    aggr_all_kernel<<<gaA, 256, 0, stream>>>(xb16, xg16, off, elist, Aline, Ag2b, Ab2g);
    combine_mfma_kernel<<<tbB, 256, 0, stream>>>(xb16, Aline, Ag2b, WtBus[0], bsb[0], H1b, nullptr, NB, 3);
    combine_mfma_kernel<<<tbG, 256, 0, stream>>>(xg16, Ab2g, nullptr, WtGen[0], bsg[0], H1g, nullptr, NG, 2);

    // ---- layer 1 (outputs only pooled -> fused column-sum) ----
    aggr_all_kernel<<<gaA, 256, 0, stream>>>(H1b, H1g, off, elist, Aline, Ag2b, Ab2g);
    combine_mfma_kernel<<<tbB, 256, 0, stream>>>(H1b, Aline, Ag2b, WtBus[1], bsb[1], nullptr, pool, NB, 3);
    combine_mfma_kernel<<<tbG, 256, 0, stream>>>(H1g, Ab2g, nullptr, WtGen[1], bsg[1], nullptr, pool + 64, NG, 2);

    // ---- head ----
    head_kernel<<<1, 128, 0, stream>>>(pool, Wh, bh, Wo, bo, (float*)d_out);
}

// Round 16
// 450.035 us; speedup vs baseline: 1.0549x; 1.0549x over previous
//
#include <hip/hip_runtime.h>

#define NB 100000
#define NG 20000
#define EL 1000000
#define EX 200000
#define NSEG (2 * NB + NG)   // concatenated CSR rows: [line->bus | g2b->bus | b2g->gen]
#define NE (EL + 2 * EX)
#define TILE 2048
#define NTILES ((NSEG + TILE - 1) / TILE)   // 108 (must be <= 256)
#define WROW 72              // Wt row stride (ushorts): 144 B, 16-aligned
#define WMAT (64 * WROW)     // 4608 ushorts per 64x64 matrix
#define AST 200              // A-tile row stride (ushorts)
#define FPB 128              // fill blocks per partition
#define PSEG (NSEG / 8)      // 27500 segments per partition

typedef __attribute__((ext_vector_type(8))) short bf16x8;
typedef __attribute__((ext_vector_type(4))) float f32x4;

static __device__ __forceinline__ int uni(int x) { return __builtin_amdgcn_readfirstlane(x); }

static __device__ __forceinline__ unsigned short f2bf(float x) {   // RNE f32->bf16
    unsigned u = __float_as_uint(x);
    u += 0x7FFF + ((u >> 16) & 1);
    return (unsigned short)(u >> 16);
}
static __device__ __forceinline__ float bf2f(unsigned short s) {
    return __uint_as_float(((unsigned)s) << 16);
}

// ---- fp32 -> bf16 array convert ----
__global__ void cvt_kernel(const float* __restrict__ src, unsigned short* __restrict__ dst, int n) {
    int i = (blockIdx.x * blockDim.x + threadIdx.x) * 4;
    if (i < n) {
        float4 f = *(const float4*)(src + i);
        ushort4 u = { f2bf(f.x), f2bf(f.y), f2bf(f.z), f2bf(f.w) };
        *(ushort4*)(dst + i) = u;
    }
}

// ---- fused degree count over all three edge lists (plain loads — R15's nt loads
//      regressed fill 65->78 µs without reducing WRITE; reverted everywhere) ----
__global__ void count_all_kernel(const int* __restrict__ ld, const int* __restrict__ gd,
                                 const int* __restrict__ bd, int* __restrict__ deg) {
    int i = blockIdx.x * blockDim.x + threadIdx.x;
    if (i < EL)               atomicAdd(&deg[ld[i]], 1);
    else if (i < EL + EX)     atomicAdd(&deg[NB + gd[i - EL]], 1);
    else if (i < NE)          atomicAdd(&deg[2 * NB + bd[i - EL - EX]], 1);
}

// ---- hierarchical scan ----
__global__ __launch_bounds__(256) void scan_part_kernel(const int* __restrict__ deg,
                                                        int* __restrict__ partial, int n) {
    __shared__ int ls[256];
    const int t = threadIdx.x;
    const int base = blockIdx.x * TILE;
    int s = 0;
    for (int i = t; i < TILE; i += 256) {
        int idx = base + i;
        s += (idx < n) ? deg[idx] : 0;
    }
    ls[t] = s;
    __syncthreads();
    for (int d = 128; d > 0; d >>= 1) {
        if (t < d) ls[t] += ls[t + d];
        __syncthreads();
    }
    if (t == 0) partial[blockIdx.x] = ls[0];
}

__global__ __launch_bounds__(256) void scan_top_kernel(int* __restrict__ partial,
                                                       int* __restrict__ off, int nparts, int n) {
    __shared__ int ls[256];
    const int t = threadIdx.x;
    ls[t] = (t < nparts) ? partial[t] : 0;
    __syncthreads();
    for (int d = 1; d < 256; d <<= 1) {
        int x = (t >= d) ? ls[t - d] : 0;
        __syncthreads();
        ls[t] += x;
        __syncthreads();
    }
    if (t < nparts) partial[t] = (t == 0) ? 0 : ls[t - 1];
    if (t == 255) off[n] = ls[255];
}

__global__ __launch_bounds__(256) void scan_write_kernel(const int* __restrict__ deg,
                                                         const int* __restrict__ partial,
                                                         int* __restrict__ off,
                                                         int* __restrict__ cur, int n) {
    __shared__ int ls[256];
    const int t = threadIdx.x;
    const int b0 = blockIdx.x * TILE + t * 8;
    int local[8];
    int s = 0;
#pragma unroll
    for (int j = 0; j < 8; ++j) {
        int idx = b0 + j;
        local[j] = (idx < n) ? deg[idx] : 0;
        s += local[j];
    }
    ls[t] = s;
    __syncthreads();
    for (int d = 1; d < 256; d <<= 1) {
        int x = (t >= d) ? ls[t - d] : 0;
        __syncthreads();
        ls[t] += x;
        __syncthreads();
    }
    int run = partial[blockIdx.x] + ((t == 0) ? 0 : ls[t - 1]);
#pragma unroll
    for (int j = 0; j < 8; ++j) {
        int idx = b0 + j;
        if (idx < n) { off[idx] = run; cur[idx] = run; run += local[j]; }
    }
}

// ---- partitioned CSR fill (R12/R14 known-good form, ~65 µs structural floor) ----
__global__ __launch_bounds__(256) void fill_part_kernel(
    const int* __restrict__ ls, const int* __restrict__ ld,
    const int* __restrict__ gs, const int* __restrict__ gd,
    const int* __restrict__ bs, const int* __restrict__ bd,
    int* __restrict__ cursor, int* __restrict__ elist)
{
    const int p = blockIdx.x & 7;
    const int q = blockIdx.x >> 3;
    const int lo = p * PSEG;
    const int hi = lo + PSEG;
    for (int i = q * 256 + threadIdx.x; i < NE; i += FPB * 256) {
        int src, seg;
        if (i < EL)           { src = ls[i];           seg = ld[i]; }
        else if (i < EL + EX) { src = gs[i - EL];      seg = NB + gd[i - EL]; }
        else                  { src = bs[i - EL - EX]; seg = 2 * NB + bd[i - EL - EX]; }
        if (seg >= lo && seg < hi) {
            int pos = atomicAdd(&cursor[seg], 1);
            elist[pos] = src;
        }
    }
}

// ---- weight prep: Wt[n*72+k] = bf16(W[k*64+n]) for 10 matrices (one block each) ----
struct WPrep { const float* src[10]; unsigned short* dst[10]; };
__global__ __launch_bounds__(256) void wprep_kernel(WPrep p) {
    const float* __restrict__ s = p.src[blockIdx.x];
    unsigned short* __restrict__ d = p.dst[blockIdx.x];
    for (int idx = threadIdx.x; idx < 4096; idx += 256) {
        int k = idx >> 6, nn = idx & 63;
        d[nn * WROW + k] = f2bf(s[idx]);
    }
}

// ---- mean over bf16 CSR segment, 8 gathers in flight ----
static __device__ __forceinline__ float seg_mean16(const unsigned short* __restrict__ h,
                                                   const int* __restrict__ elist,
                                                   int s0, int e0, int lane) {
    float s = 0.f;
    int e = s0;
    for (; e + 8 <= e0; e += 8) {
        int i0 = elist[e],     i1 = elist[e + 1], i2 = elist[e + 2], i3 = elist[e + 3];
        int i4 = elist[e + 4], i5 = elist[e + 5], i6 = elist[e + 6], i7 = elist[e + 7];
        float v0 = bf2f(h[(size_t)i0 * 64 + lane]), v1 = bf2f(h[(size_t)i1 * 64 + lane]);
        float v2 = bf2f(h[(size_t)i2 * 64 + lane]), v3 = bf2f(h[(size_t)i3 * 64 + lane]);
        float v4 = bf2f(h[(size_t)i4 * 64 + lane]), v5 = bf2f(h[(size_t)i5 * 64 + lane]);
        float v6 = bf2f(h[(size_t)i6 * 64 + lane]), v7 = bf2f(h[(size_t)i7 * 64 + lane]);
        s += ((v0 + v1) + (v2 + v3)) + ((v4 + v5) + (v6 + v7));
    }
    for (; e + 2 <= e0; e += 2) {
        int i0 = elist[e], i1 = elist[e + 1];
        s += bf2f(h[(size_t)i0 * 64 + lane]) + bf2f(h[(size_t)i1 * 64 + lane]);
    }
    if (e < e0) s += bf2f(h[(size_t)elist[e] * 64 + lane]);
    return s / fmaxf((float)(e0 - s0), 1.f);
}

// ---- merged aggregation (R10 form; bf16 in/out) ----
__global__ __launch_bounds__(256) void aggr_all_kernel(
    const unsigned short* __restrict__ hb, const unsigned short* __restrict__ hg,
    const int* __restrict__ off, const int* __restrict__ elist,
    unsigned short* __restrict__ Aline, unsigned short* __restrict__ Ag2b,
    unsigned short* __restrict__ Ab2g)
{
    const int lane = threadIdx.x & 63;
    int w = uni(blockIdx.x * 4 + (threadIdx.x >> 6));
    if (w < NB) {
        Aline[(size_t)w * 64 + lane] = f2bf(seg_mean16(hb, elist, off[w], off[w + 1], lane));
        Ag2b[(size_t)w * 64 + lane]  = f2bf(seg_mean16(hg, elist, off[NB + w], off[NB + w + 1], lane));
    } else if (w < NB + NG) {
        int g = w - NB;
        Ab2g[(size_t)g * 64 + lane] = f2bf(seg_mean16(hb, elist, off[2 * NB + g], off[2 * NB + g + 1], lane));
    }
}

// ---- MFMA combine: out16 = bf16(relu([h|A1|A2] @ Wt^T + b)).
//      B-fragments read DIRECTLY from global Wt (27.6 KB, shared by all blocks ->
//      L1/L2-resident after first touch). Drops the 27.6 KB Wtile + its per-block
//      copy loop: LDS 53.2 -> 25.6 KB => blocks/CU 2-3 -> 6. A-tile structure
//      unchanged (R10-validated). ----
__global__ __launch_bounds__(256) void combine_mfma_kernel(
    const unsigned short* __restrict__ h, const unsigned short* __restrict__ A1,
    const unsigned short* __restrict__ A2,
    const unsigned short* __restrict__ Wt, const float* __restrict__ bias,
    unsigned short* __restrict__ out, float* __restrict__ pool, int n, int nmat)
{
    __shared__ __attribute__((aligned(16))) unsigned short Atile[64 * AST]; // 25.6 KB
    __shared__ float pred[64];
    const int t = threadIdx.x;
    const int base = blockIdx.x * 64;

    if (t < 64) pred[t] = 0.f;

#pragma unroll
    for (int i = 0; i < 4; ++i) {
        int flat = i * 1024 + t * 4;
        int r = flat >> 6, c = flat & 63;
        bool ok = (base + r) < n;
        ushort4 z = {0, 0, 0, 0};
        size_t g = (size_t)(base + r) * 64 + c;
        *(ushort4*)&Atile[r * AST + c]      = ok ? *(const ushort4*)(h + g)  : z;
        *(ushort4*)&Atile[r * AST + 64 + c] = ok ? *(const ushort4*)(A1 + g) : z;
        if (nmat == 3)
            *(ushort4*)&Atile[r * AST + 128 + c] = ok ? *(const ushort4*)(A2 + g) : z;
    }
    __syncthreads();

    const int lane = t & 63;
    const int w = t >> 6;
    const int l15 = lane & 15;
    const int q = lane >> 4;
    f32x4 acc[4];
#pragma unroll
    for (int c = 0; c < 4; ++c) acc[c] = (f32x4){0.f, 0.f, 0.f, 0.f};

    const int ksteps = nmat * 2;
    for (int ks = 0; ks < ksteps; ++ks) {
        bf16x8 av = *(const bf16x8*)&Atile[(w * 16 + l15) * AST + ks * 32 + q * 8];
#pragma unroll
        for (int c = 0; c < 4; ++c) {
            bf16x8 bv = *(const bf16x8*)&Wt[(ks >> 1) * WMAT + (c * 16 + l15) * WROW + (ks & 1) * 32 + q * 8];
            acc[c] = __builtin_amdgcn_mfma_f32_16x16x32_bf16(av, bv, acc[c], 0, 0, 0);
        }
    }

    if (pool == nullptr) {
#pragma unroll
        for (int c = 0; c < 4; ++c) {
            const int col = c * 16 + l15;
            const float bv = bias[col];
#pragma unroll
            for (int reg = 0; reg < 4; ++reg) {
                int row = base + w * 16 + q * 4 + reg;
                if (row < n) out[(size_t)row * 64 + col] = f2bf(fmaxf(acc[c][reg] + bv, 0.f));
            }
        }
    } else {
#pragma unroll
        for (int c = 0; c < 4; ++c) {
            const int col = c * 16 + l15;
            const float bv = bias[col];
            float s = 0.f;
#pragma unroll
            for (int reg = 0; reg < 4; ++reg) {
                int row = base + w * 16 + q * 4 + reg;
                if (row < n) s += fmaxf(acc[c][reg] + bv, 0.f);
            }
            atomicAdd(&pred[col], s);
        }
        __syncthreads();
        if (t < 64) atomicAdd(&pool[t], pred[t]);
    }
}

// ---- head: out = relu(g @ Wh + bh) @ Wo + bo ----
__global__ void head_kernel(const float* __restrict__ pool,
                            const float* __restrict__ Wh, const float* __restrict__ bh,
                            const float* __restrict__ Wo, const float* __restrict__ bo,
                            float* __restrict__ out)
{
    __shared__ float g[128];
    __shared__ float hid[64];
    int t = threadIdx.x;  // 128 threads
    g[t] = pool[t];
    __syncthreads();
    if (t < 64) {
        float a = bh[t];
        for (int i = 0; i < 128; ++i) a += g[i] * Wh[i * 64 + t];
        hid[t] = fmaxf(a, 0.f);
    }
    __syncthreads();
    if (t < 16) {
        float a = bo[t];
        for (int j = 0; j < 64; ++j) a += hid[j] * Wo[j * 16 + t];
        out[t] = a;
    }
}

extern "C" void kernel_launch(void* const* d_in, const int* in_sizes, int n_in,
                              void* d_out, int out_size, void* d_ws, size_t ws_size,
                              hipStream_t stream)
{
    const float* x_bus   = (const float*)d_in[0];
    const float* x_gen   = (const float*)d_in[1];
    const int* line_src  = (const int*)d_in[2];
    const int* line_dst  = (const int*)d_in[3];
    const int* g2b_src   = (const int*)d_in[4];
    const int* g2b_dst   = (const int*)d_in[5];
    const int* b2g_src   = (const int*)d_in[6];
    const int* b2g_dst   = (const int*)d_in[7];
    const float* Wsb[2]  = {(const float*)d_in[8],  (const float*)d_in[15]};
    const float* Wsg[2]  = {(const float*)d_in[9],  (const float*)d_in[16]};
    const float* Wl[2]   = {(const float*)d_in[10], (const float*)d_in[17]};
    const float* Wg2b[2] = {(const float*)d_in[11], (const float*)d_in[18]};
    const float* Wb2g[2] = {(const float*)d_in[12], (const float*)d_in[19]};
    const float* bsb[2]  = {(const float*)d_in[13], (const float*)d_in[20]};
    const float* bsg[2]  = {(const float*)d_in[14], (const float*)d_in[21]};
    const float* Wh = (const float*)d_in[22];
    const float* bh = (const float*)d_in[23];
    const float* Wo = (const float*)d_in[24];
    const float* bo = (const float*)d_in[25];
    (void)in_sizes; (void)n_in; (void)out_size; (void)ws_size;

    char* wsB = (char*)d_ws;
    size_t o = 0;
    auto alloc_f = [&](size_t nelem) { o = (o + 15) & ~(size_t)15; float* p = (float*)(wsB + o); o += nelem * sizeof(float); return p; };
    auto alloc_i = [&](size_t nelem) { o = (o + 15) & ~(size_t)15; int* p = (int*)(wsB + o); o += nelem * sizeof(int); return p; };
    auto alloc_u = [&](size_t nelem) { o = (o + 15) & ~(size_t)15; unsigned short* p = (unsigned short*)(wsB + o); o += nelem * sizeof(unsigned short); return p; };

    unsigned short* xb16  = alloc_u((size_t)NB * 64);
    unsigned short* xg16  = alloc_u((size_t)NG * 64);
    unsigned short* H1b   = alloc_u((size_t)NB * 64);
    unsigned short* H1g   = alloc_u((size_t)NG * 64);
    unsigned short* Aline = alloc_u((size_t)NB * 64);
    unsigned short* Ag2b  = alloc_u((size_t)NB * 64);
    unsigned short* Ab2g  = alloc_u((size_t)NG * 64);
    int*   elist = alloc_i(NE);
    int*   deg   = alloc_i(NSEG);
    int*   off   = alloc_i(NSEG + 1);
    int*   cur   = alloc_i(NSEG);
    int*   part  = alloc_i(256);
    float* pool  = alloc_f(128);
    unsigned short* WtBus[2] = { alloc_u(3 * WMAT), alloc_u(3 * WMAT) };
    unsigned short* WtGen[2] = { alloc_u(2 * WMAT), alloc_u(2 * WMAT) };

    // ---- weight prep + input convert (independent of CSR) ----
    WPrep wp;
    for (int l = 0; l < 2; ++l) {
        wp.src[l * 5 + 0] = Wsb[l];  wp.dst[l * 5 + 0] = WtBus[l] + 0 * WMAT;
        wp.src[l * 5 + 1] = Wl[l];   wp.dst[l * 5 + 1] = WtBus[l] + 1 * WMAT;
        wp.src[l * 5 + 2] = Wg2b[l]; wp.dst[l * 5 + 2] = WtBus[l] + 2 * WMAT;
        wp.src[l * 5 + 3] = Wsg[l];  wp.dst[l * 5 + 3] = WtGen[l] + 0 * WMAT;
        wp.src[l * 5 + 4] = Wb2g[l]; wp.dst[l * 5 + 4] = WtGen[l] + 1 * WMAT;
    }
    wprep_kernel<<<10, 256, 0, stream>>>(wp);
    cvt_kernel<<<(NB * 64 / 4 + 255) / 256, 256, 0, stream>>>(x_bus, xb16, NB * 64);
    cvt_kernel<<<(NG * 64 / 4 + 255) / 256, 256, 0, stream>>>(x_gen, xg16, NG * 64);

    // ---- CSR build ----
    hipMemsetAsync(deg, 0, NSEG * sizeof(int), stream);
    hipMemsetAsync(pool, 0, 128 * sizeof(float), stream);
    count_all_kernel<<<(NE + 255) / 256, 256, 0, stream>>>(line_dst, g2b_dst, b2g_dst, deg);
    scan_part_kernel<<<NTILES, 256, 0, stream>>>(deg, part, NSEG);
    scan_top_kernel<<<1, 256, 0, stream>>>(part, off, NTILES, NSEG);
    scan_write_kernel<<<NTILES, 256, 0, stream>>>(deg, part, off, cur, NSEG);
    fill_part_kernel<<<8 * FPB, 256, 0, stream>>>(line_src, line_dst, g2b_src, g2b_dst,
                                                  b2g_src, b2g_dst, cur, elist);

    const int gaA = (NB + NG + 3) / 4;
    const int tbB = (NB + 63) / 64, tbG = (NG + 63) / 64;

    // ---- layer 0 ----
    aggr_all_kernel<<<gaA, 256, 0, stream>>>(xb16, xg16, off, elist, Aline, Ag2b, Ab2g);
    combine_mfma_kernel<<<tbB, 256, 0, stream>>>(xb16, Aline, Ag2b, WtBus[0], bsb[0], H1b, nullptr, NB, 3);
    combine_mfma_kernel<<<tbG, 256, 0, stream>>>(xg16, Ab2g, nullptr, WtGen[0], bsg[0], H1g, nullptr, NG, 2);

    // ---- layer 1 (outputs only pooled -> fused column-sum) ----
    aggr_all_kernel<<<gaA, 256, 0, stream>>>(H1b, H1g, off, elist, Aline, Ag2b, Ab2g);
    combine_mfma_kernel<<<tbB, 256, 0, stream>>>(H1b, Aline, Ag2b, WtBus[1], bsb[1], nullptr, pool, NB, 3);
    combine_mfma_kernel<<<tbG, 256, 0, stream>>>(H1g, Ab2g, nullptr, WtGen[1], bsg[1], nullptr, pool + 64, NG, 2);

    // ---- head ----
    head_kernel<<<1, 128, 0, stream>>>(pool, Wh, bh, Wo, bo, (float*)d_out);
}